// Round 2
// baseline (365.201 us; speedup 1.0000x reference)
//
#include <hip/hip_runtime.h>
#include <stdint.h>

typedef __bf16 bf16;
typedef __attribute__((ext_vector_type(4))) float f32x4;
typedef __attribute__((ext_vector_type(8))) bf16 bf16x8;
typedef __attribute__((ext_vector_type(4))) bf16 bf16x4;
typedef __attribute__((ext_vector_type(4))) float f4;

#define HQ_ 16
#define HKV_ 4
#define S_ 2048
#define D_ 2048

// async global->LDS, 16B per lane. lds_base must be wave-uniform; HW adds lane*16.
static __device__ __forceinline__ void gload16(const void* g, void* lds_base) {
  __builtin_amdgcn_global_load_lds(
      (const __attribute__((address_space(1))) void*)g,
      (__attribute__((address_space(3))) void*)lds_base, 16, 0, 0);
}

// ---------------- cast x: f32 -> bf16, 4 elems/thread ----------------
__global__ __launch_bounds__(256) void cast_x(const float* __restrict__ in,
                                              bf16* __restrict__ out, int n4) {
  int i = blockIdx.x * 256 + threadIdx.x;
  if (i >= n4) return;
  f4 v = *(const f4*)(in + (size_t)i * 4);
  bf16x4 o;
  o[0] = (bf16)v[0]; o[1] = (bf16)v[1]; o[2] = (bf16)v[2]; o[3] = (bf16)v[3];
  *(bf16x4*)(out + (size_t)i * 4) = o;
}

// -------- transpose+cast weights: W[K][N] f32 -> Wt[N][K] bf16 --------
__global__ __launch_bounds__(256) void transW(const float* __restrict__ W,
                                              bf16* __restrict__ Wt, int K, int N) {
  __shared__ float tile[32][33];
  int n0 = blockIdx.x * 32, k0 = blockIdx.y * 32;
  int tx = threadIdx.x & 31, ty = threadIdx.x >> 5;
#pragma unroll
  for (int i = 0; i < 4; ++i)
    tile[ty + i * 8][tx] = W[(size_t)(k0 + ty + i * 8) * N + n0 + tx];
  __syncthreads();
#pragma unroll
  for (int i = 0; i < 4; ++i)
    Wt[(size_t)(n0 + ty + i * 8) * K + k0 + tx] = (bf16)tile[tx][ty + i * 8];
}

// ---------------- bf16 GEMM: C[M,N] = A[M,K] * Bt[N,K]^T ----------------
// 128x128 tile, BK=32, 4 waves (2x2), 16x16x32 MFMA.
// MODE 0: Q-layout bf16 [B,HQ,S,128]   MODE 1: K-layout bf16 [B,HKV,S,128]
// MODE 2: V^T-layout bf16 [B,HKV,128,S] MODE 3: f32 row-major [M,N]
template <int MODE>
__global__ __launch_bounds__(256, 2)
void gemm128(const bf16* __restrict__ A, const bf16* __restrict__ Bt,
             void* __restrict__ out, int K, int N) {
  __shared__ __align__(16) bf16 As[128 * 32];
  __shared__ __align__(16) bf16 Bs[128 * 32];
  const int t = threadIdx.x;
  const int lane = t & 63, wave = t >> 6;
  const int l16 = lane & 15, l4 = lane >> 4;
  const int wr = wave >> 1, wc = wave & 1;
  const int m0 = blockIdx.y * 128, n0 = blockIdx.x * 128;

  f32x4 acc[4][4] = {};

  // staging: slot s in 0..511 per matrix; row = s>>2 (32-elem rows), chunk = s&3
  // swizzle: LDS chunk c holds global chunk c ^ ((row>>1)&3)  (2-way banks max)
  const int r0 = t >> 2, c0 = ((t & 3) ^ ((t >> 3) & 3));
  const int r1 = r0 + 64, c1 = ((t & 3) ^ ((r1 >> 1) & 3));
  const bf16* aS0 = A + (size_t)(m0 + r0) * K + c0 * 8;
  const bf16* aS1 = A + (size_t)(m0 + r1) * K + c1 * 8;
  const bf16* bS0 = Bt + (size_t)(n0 + r0) * K + c0 * 8;
  const bf16* bS1 = Bt + (size_t)(n0 + r1) * K + c1 * 8;
  bf16* aL0 = &As[(wave * 64) * 8];
  bf16* aL1 = &As[(256 + wave * 64) * 8];
  bf16* bL0 = &Bs[(wave * 64) * 8];
  bf16* bL1 = &Bs[(256 + wave * 64) * 8];

  const int nk = K >> 5;
  for (int kt = 0; kt < nk; ++kt) {
    gload16(aS0, aL0); gload16(aS1, aL1);
    gload16(bS0, bL0); gload16(bS1, bL1);
    aS0 += 32; aS1 += 32; bS0 += 32; bS1 += 32;
    asm volatile("s_waitcnt vmcnt(0)");
    __syncthreads();
    bf16x8 af[4], bb[4];
#pragma unroll
    for (int mf = 0; mf < 4; ++mf) {
      int row = wr * 64 + mf * 16 + l16;
      af[mf] = *(const bf16x8*)&As[row * 32 + (l4 ^ ((row >> 1) & 3)) * 8];
    }
#pragma unroll
    for (int nf = 0; nf < 4; ++nf) {
      int row = wc * 64 + nf * 16 + l16;
      bb[nf] = *(const bf16x8*)&Bs[row * 32 + (l4 ^ ((row >> 1) & 3)) * 8];
    }
#pragma unroll
    for (int mf = 0; mf < 4; ++mf)
#pragma unroll
      for (int nf = 0; nf < 4; ++nf)
        acc[mf][nf] = __builtin_amdgcn_mfma_f32_16x16x32_bf16(af[mf], bb[nf],
                                                              acc[mf][nf], 0, 0, 0);
    __syncthreads();
  }

#pragma unroll
  for (int mf = 0; mf < 4; ++mf)
#pragma unroll
    for (int nf = 0; nf < 4; ++nf)
#pragma unroll
      for (int rg = 0; rg < 4; ++rg) {
        int r = m0 + wr * 64 + mf * 16 + l4 * 4 + rg;  // token index
        int c = n0 + wc * 64 + nf * 16 + l16;          // output column
        float v = acc[mf][nf][rg];
        if constexpr (MODE == 0) {
          int b = r >> 11, s = r & 2047, h = c >> 7, dd = c & 127;
          ((bf16*)out)[(((size_t)(b * HQ_ + h)) * S_ + s) * 128 + dd] = (bf16)v;
        } else if constexpr (MODE == 1) {
          int b = r >> 11, s = r & 2047, h = c >> 7, dd = c & 127;
          ((bf16*)out)[(((size_t)(b * HKV_ + h)) * S_ + s) * 128 + dd] = (bf16)v;
        } else if constexpr (MODE == 2) {
          int b = r >> 11, s = r & 2047, h = c >> 7, dd = c & 127;
          ((bf16*)out)[(((size_t)(b * HKV_ + h)) * 128 + dd) * S_ + s] = (bf16)v;
        } else {
          ((float*)out)[(size_t)r * N + c] = v;
        }
      }
}

// ---------------- flash attention, non-causal, d=128 ----------------
// grid (S/128, HQ, B); 256 thr = 4 waves; wave owns 32 q-rows; KV tile = 64.
__global__ __launch_bounds__(256, 2)
void attn_fwd(const bf16* __restrict__ Qb, const bf16* __restrict__ Kb,
              const bf16* __restrict__ Vtb, bf16* __restrict__ AO) {
  const int qt = blockIdx.x, h = blockIdx.y, b = blockIdx.z;
  const int hkv = h >> 2;  // REP = 4
  const int t = threadIdx.x, lane = t & 63, wave = t >> 6;
  const int l16 = lane & 15, l4 = lane >> 4;
  const bf16* Qg = Qb + ((size_t)(b * HQ_ + h) * S_ + qt * 128) * 128;
  const bf16* Kg = Kb + (size_t)(b * HKV_ + hkv) * S_ * 128;
  const bf16* Vg = Vtb + (size_t)(b * HKV_ + hkv) * 128 * S_;

  __shared__ __align__(16) bf16 Ks[64 * 128];   // [kk][d], chunk ^= kk&7
  __shared__ __align__(16) bf16 Vs[128 * 64];   // [dd][kk], chunk ^= dd&7
  __shared__ __align__(16) bf16 Ps[128 * 64];   // [q][kk],  chunk ^= q&7

  // Q fragments in registers: [m-frag][k-step]
  bf16x8 qf[2][4];
#pragma unroll
  for (int mf = 0; mf < 2; ++mf)
#pragma unroll
    for (int ks = 0; ks < 4; ++ks)
      qf[mf][ks] = *(const bf16x8*)&Qg[(size_t)(wave * 32 + mf * 16 + l16) * 128 +
                                       ks * 32 + l4 * 8];

  f32x4 ao[2][8] = {};
  float mrun[2][4], lrun[2][4];
#pragma unroll
  for (int m = 0; m < 2; ++m)
#pragma unroll
    for (int rg = 0; rg < 4; ++rg) { mrun[m][rg] = -1e30f; lrun[m][rg] = 0.f; }

  const float C = 1.4426950408889634f * 0.08838834764831845f;  // log2(e)/sqrt(128)

  for (int nt = 0; nt < S_ / 64; ++nt) {
    // stage K and V^T tiles (pre-swizzled global source, linear LDS dest)
#pragma unroll
    for (int i = 0; i < 4; ++i) {
      int s = i * 256 + t;
      int kr = s >> 4, kc = (s & 15) ^ (kr & 7);
      gload16(&Kg[(size_t)(nt * 64 + kr) * 128 + kc * 8], &Ks[(i * 256 + wave * 64) * 8]);
      int vr = s >> 3, vc = (s & 7) ^ (vr & 7);
      gload16(&Vg[(size_t)vr * S_ + nt * 64 + vc * 8], &Vs[(i * 256 + wave * 64) * 8]);
    }
    asm volatile("s_waitcnt vmcnt(0)");
    __syncthreads();

    // ---- QK^T : S[q][kk], q in wave's 32 rows, kk in 0..63 ----
    f32x4 sc[2][4] = {};
#pragma unroll
    for (int ks = 0; ks < 4; ++ks) {
      bf16x8 kb[4];
#pragma unroll
      for (int nf = 0; nf < 4; ++nf) {
        int row = nf * 16 + l16;
        int ch = (ks * 4 + l4) ^ (row & 7);
        kb[nf] = *(const bf16x8*)&Ks[row * 128 + ch * 8];
      }
#pragma unroll
      for (int m = 0; m < 2; ++m)
#pragma unroll
        for (int nf = 0; nf < 4; ++nf)
          sc[m][nf] = __builtin_amdgcn_mfma_f32_16x16x32_bf16(qf[m][ks], kb[nf],
                                                              sc[m][nf], 0, 0, 0);
    }

    // ---- online softmax (rows split: in-lane over nf, butterfly over l16) ----
#pragma unroll
    for (int m = 0; m < 2; ++m) {
#pragma unroll
      for (int nf = 0; nf < 4; ++nf)
#pragma unroll
        for (int rg = 0; rg < 4; ++rg) sc[m][nf][rg] *= C;
#pragma unroll
      for (int rg = 0; rg < 4; ++rg) {
        float mx = fmaxf(fmaxf(sc[m][0][rg], sc[m][1][rg]),
                         fmaxf(sc[m][2][rg], sc[m][3][rg]));
        mx = fmaxf(mx, __shfl_xor(mx, 1));
        mx = fmaxf(mx, __shfl_xor(mx, 2));
        mx = fmaxf(mx, __shfl_xor(mx, 4));
        mx = fmaxf(mx, __shfl_xor(mx, 8));
        float mnew = fmaxf(mrun[m][rg], mx);
        float alpha = exp2f(mrun[m][rg] - mnew);
        mrun[m][rg] = mnew;
        float ps = 0.f;
#pragma unroll
        for (int nf = 0; nf < 4; ++nf) {
          float p = exp2f(sc[m][nf][rg] - mnew);
          sc[m][nf][rg] = p;
          ps += p;
        }
        ps += __shfl_xor(ps, 1); ps += __shfl_xor(ps, 2);
        ps += __shfl_xor(ps, 4); ps += __shfl_xor(ps, 8);
        lrun[m][rg] = lrun[m][rg] * alpha + ps;
#pragma unroll
        for (int nfd = 0; nfd < 8; ++nfd) ao[m][nfd][rg] *= alpha;
      }
    }

    // ---- write P to LDS (wave-local rows; swizzled) ----
#pragma unroll
    for (int m = 0; m < 2; ++m)
#pragma unroll
      for (int rg = 0; rg < 4; ++rg) {
        int q = wave * 32 + m * 16 + l4 * 4 + rg;
#pragma unroll
        for (int nf = 0; nf < 4; ++nf) {
          int kk = nf * 16 + l16;
          int ch = (kk >> 3) ^ (q & 7);
          Ps[q * 64 + ch * 8 + (kk & 7)] = (bf16)sc[m][nf][rg];
        }
      }

    // ---- PV : ao[q][dd] += P[q][kk] * V[kk][dd] (P rows wave-local) ----
#pragma unroll
    for (int ks2 = 0; ks2 < 2; ++ks2) {
      bf16x8 pa[2];
#pragma unroll
      for (int m = 0; m < 2; ++m) {
        int q = wave * 32 + m * 16 + l16;
        int ch = (ks2 * 4 + l4) ^ (q & 7);
        pa[m] = *(const bf16x8*)&Ps[q * 64 + ch * 8];
      }
#pragma unroll
      for (int nfd = 0; nfd < 8; ++nfd) {
        int dd = nfd * 16 + l16;
        int ch = (ks2 * 4 + l4) ^ (dd & 7);
        bf16x8 vb = *(const bf16x8*)&Vs[dd * 64 + ch * 8];
#pragma unroll
        for (int m = 0; m < 2; ++m)
          ao[m][nfd] = __builtin_amdgcn_mfma_f32_16x16x32_bf16(pa[m], vb,
                                                               ao[m][nfd], 0, 0, 0);
      }
    }
    __syncthreads();  // K/V/P reusable next tile
  }

  // ---- epilogue: AO[token][HQ*128] bf16 ----
#pragma unroll
  for (int m = 0; m < 2; ++m)
#pragma unroll
    for (int rg = 0; rg < 4; ++rg) {
      float inv = 1.f / lrun[m][rg];
      int sg = qt * 128 + wave * 32 + m * 16 + l4 * 4 + rg;
#pragma unroll
      for (int nfd = 0; nfd < 8; ++nfd) {
        int dd = nfd * 16 + l16;
        AO[((size_t)(b * S_ + sg)) * D_ + h * 128 + dd] = (bf16)(ao[m][nfd][rg] * inv);
      }
    }
}

extern "C" void kernel_launch(void* const* d_in, const int* in_sizes, int n_in,
                              void* d_out, int out_size, void* d_ws, size_t ws_size,
                              hipStream_t stream) {
  const float* x  = (const float*)d_in[0];
  const float* Wq = (const float*)d_in[1];
  const float* Wk = (const float*)d_in[2];
  const float* Wv = (const float*)d_in[3];
  const float* Wo = (const float*)d_in[4];

  char* ws = (char*)d_ws;
  bf16* xb  = (bf16*)(ws + 0);          // 16 MiB  [4096][2048]; reused as AO later
  bf16* Wqt = (bf16*)(ws + 16777216);   // 8 MiB   [2048][2048] (N-major)
  bf16* Wkt = (bf16*)(ws + 25165824);   // 2 MiB   [512][2048]
  bf16* Wvt = (bf16*)(ws + 27262976);   // 2 MiB   [512][2048]
  bf16* Wot = (bf16*)(ws + 29360128);   // 8 MiB   [2048][2048]
  bf16* Qb  = (bf16*)(ws + 37748736);   // 16 MiB  [B,HQ,S,128]
  bf16* Kb  = (bf16*)(ws + 54525952);   // 4 MiB   [B,HKV,S,128]
  bf16* Vtb = (bf16*)(ws + 58720256);   // 4 MiB   [B,HKV,128,S]
  bf16* AO  = xb;                       // alias: xb dead after V projection

  cast_x<<<8192, 256, 0, stream>>>(x, xb, 2097152);
  transW<<<dim3(64, 64), 256, 0, stream>>>(Wq, Wqt, 2048, 2048);
  transW<<<dim3(16, 64), 256, 0, stream>>>(Wk, Wkt, 2048, 512);
  transW<<<dim3(16, 64), 256, 0, stream>>>(Wv, Wvt, 2048, 512);
  transW<<<dim3(64, 64), 256, 0, stream>>>(Wo, Wot, 2048, 2048);

  gemm128<0><<<dim3(16, 32), 256, 0, stream>>>(xb, Wqt, (void*)Qb, 2048, 2048);
  gemm128<1><<<dim3(4, 32), 256, 0, stream>>>(xb, Wkt, (void*)Kb, 2048, 512);
  gemm128<2><<<dim3(4, 32), 256, 0, stream>>>(xb, Wvt, (void*)Vtb, 2048, 512);

  attn_fwd<<<dim3(16, 16, 2), 256, 0, stream>>>(Qb, Kb, Vtb, AO);

  gemm128<3><<<dim3(16, 32), 256, 0, stream>>>(AO, Wot, d_out, 2048, 2048);
}

// Round 3
// 300.732 us; speedup vs baseline: 1.2144x; 1.2144x over previous
//
#include <hip/hip_runtime.h>
#include <stdint.h>

typedef __bf16 bf16;
typedef __attribute__((ext_vector_type(4))) float f32x4;
typedef __attribute__((ext_vector_type(8))) bf16 bf16x8;
typedef __attribute__((ext_vector_type(4))) bf16 bf16x4;
typedef __attribute__((ext_vector_type(4))) float f4;

#define HQ_ 16
#define HKV_ 4
#define S_ 2048
#define D_ 2048

// async global->LDS, 16B per lane. lds_base must be wave-uniform; HW adds lane*16.
static __device__ __forceinline__ void gload16(const void* g, void* lds_base) {
  __builtin_amdgcn_global_load_lds(
      (const __attribute__((address_space(1))) void*)g,
      (__attribute__((address_space(3))) void*)lds_base, 16, 0, 0);
}

static __device__ __forceinline__ uint32_t pk2(float a, float b) {
  uint16_t lo = __builtin_bit_cast(uint16_t, (bf16)a);
  uint16_t hi = __builtin_bit_cast(uint16_t, (bf16)b);
  return (uint32_t)lo | ((uint32_t)hi << 16);
}

// ---------------- cast x: f32 -> bf16, 4 elems/thread ----------------
__global__ __launch_bounds__(256) void cast_x(const float* __restrict__ in,
                                              bf16* __restrict__ out, int n4) {
  int i = blockIdx.x * 256 + threadIdx.x;
  if (i >= n4) return;
  f4 v = *(const f4*)(in + (size_t)i * 4);
  bf16x4 o;
  o[0] = (bf16)v[0]; o[1] = (bf16)v[1]; o[2] = (bf16)v[2]; o[3] = (bf16)v[3];
  *(bf16x4*)(out + (size_t)i * 4) = o;
}

// -------- transpose+cast weights: W[K][N] f32 -> Wt[N][K] bf16 --------
__global__ __launch_bounds__(256) void transW(const float* __restrict__ W,
                                              bf16* __restrict__ Wt, int K, int N) {
  __shared__ float tile[32][33];
  int n0 = blockIdx.x * 32, k0 = blockIdx.y * 32;
  int tx = threadIdx.x & 31, ty = threadIdx.x >> 5;
#pragma unroll
  for (int i = 0; i < 4; ++i)
    tile[ty + i * 8][tx] = W[(size_t)(k0 + ty + i * 8) * N + n0 + tx];
  __syncthreads();
#pragma unroll
  for (int i = 0; i < 4; ++i)
    Wt[(size_t)(n0 + ty + i * 8) * K + k0 + tx] = (bf16)tile[tx][ty + i * 8];
}

// ---------------- bf16 GEMM: C[M,N] = A[M,K] * Bt[N,K]^T ----------------
// 128x128 tile, BK=32, 4 waves (2x2), 16x16x32 MFMA.  (unchanged, proven)
template <int MODE>
__global__ __launch_bounds__(256, 2)
void gemm128(const bf16* __restrict__ A, const bf16* __restrict__ Bt,
             void* __restrict__ out, int K, int N) {
  __shared__ __align__(16) bf16 As[128 * 32];
  __shared__ __align__(16) bf16 Bs[128 * 32];
  const int t = threadIdx.x;
  const int lane = t & 63, wave = t >> 6;
  const int l16 = lane & 15, l4 = lane >> 4;
  const int wr = wave >> 1, wc = wave & 1;
  const int m0 = blockIdx.y * 128, n0 = blockIdx.x * 128;

  f32x4 acc[4][4] = {};

  const int r0 = t >> 2, c0 = ((t & 3) ^ ((t >> 3) & 3));
  const int r1 = r0 + 64, c1 = ((t & 3) ^ ((r1 >> 1) & 3));
  const bf16* aS0 = A + (size_t)(m0 + r0) * K + c0 * 8;
  const bf16* aS1 = A + (size_t)(m0 + r1) * K + c1 * 8;
  const bf16* bS0 = Bt + (size_t)(n0 + r0) * K + c0 * 8;
  const bf16* bS1 = Bt + (size_t)(n0 + r1) * K + c1 * 8;
  bf16* aL0 = &As[(wave * 64) * 8];
  bf16* aL1 = &As[(256 + wave * 64) * 8];
  bf16* bL0 = &Bs[(wave * 64) * 8];
  bf16* bL1 = &Bs[(256 + wave * 64) * 8];

  const int nk = K >> 5;
  for (int kt = 0; kt < nk; ++kt) {
    gload16(aS0, aL0); gload16(aS1, aL1);
    gload16(bS0, bL0); gload16(bS1, bL1);
    aS0 += 32; aS1 += 32; bS0 += 32; bS1 += 32;
    asm volatile("s_waitcnt vmcnt(0)" ::: "memory");
    __syncthreads();
    bf16x8 af[4], bb[4];
#pragma unroll
    for (int mf = 0; mf < 4; ++mf) {
      int row = wr * 64 + mf * 16 + l16;
      af[mf] = *(const bf16x8*)&As[row * 32 + (l4 ^ ((row >> 1) & 3)) * 8];
    }
#pragma unroll
    for (int nf = 0; nf < 4; ++nf) {
      int row = wc * 64 + nf * 16 + l16;
      bb[nf] = *(const bf16x8*)&Bs[row * 32 + (l4 ^ ((row >> 1) & 3)) * 8];
    }
#pragma unroll
    for (int mf = 0; mf < 4; ++mf)
#pragma unroll
      for (int nf = 0; nf < 4; ++nf)
        acc[mf][nf] = __builtin_amdgcn_mfma_f32_16x16x32_bf16(af[mf], bb[nf],
                                                              acc[mf][nf], 0, 0, 0);
    __syncthreads();
  }

#pragma unroll
  for (int mf = 0; mf < 4; ++mf)
#pragma unroll
    for (int nf = 0; nf < 4; ++nf)
#pragma unroll
      for (int rg = 0; rg < 4; ++rg) {
        int r = m0 + wr * 64 + mf * 16 + l4 * 4 + rg;  // token index
        int c = n0 + wc * 64 + nf * 16 + l16;          // output column
        float v = acc[mf][nf][rg];
        if constexpr (MODE == 0) {
          int b = r >> 11, s = r & 2047, h = c >> 7, dd = c & 127;
          ((bf16*)out)[(((size_t)(b * HQ_ + h)) * S_ + s) * 128 + dd] = (bf16)v;
        } else if constexpr (MODE == 1) {
          int b = r >> 11, s = r & 2047, h = c >> 7, dd = c & 127;
          ((bf16*)out)[(((size_t)(b * HKV_ + h)) * S_ + s) * 128 + dd] = (bf16)v;
        } else if constexpr (MODE == 2) {
          int b = r >> 11, s = r & 2047, h = c >> 7, dd = c & 127;
          ((bf16*)out)[(((size_t)(b * HKV_ + h)) * 128 + dd) * S_ + s] = (bf16)v;
        } else {
          ((float*)out)[(size_t)r * N + c] = v;
        }
      }
}

// ---------------- flash attention, swapped-operand, double-buffered ----------------
// grid (S/128, HQ, B); 256 thr = 4 waves; wave owns 32 q-rows; KV tile = 64.
// QK^T computed as S^T = mfma(K, Q): lane holds S^T[kk=nf*16+l4*4+rg][q=qf*16+l16]
// -> row-softmax is in-lane(16) + 2 shuffles. PV as O^T = mfma(V^T, P^T).
__global__ __launch_bounds__(256, 2)
void attn_fwd(const bf16* __restrict__ Qb, const bf16* __restrict__ Kb,
              const bf16* __restrict__ Vtb, bf16* __restrict__ AO) {
  const int qt = blockIdx.x, h = blockIdx.y, b = blockIdx.z;
  const int hkv = h >> 2;  // REP = 4
  const int t = threadIdx.x, lane = t & 63, wave = t >> 6;
  const int l16 = lane & 15, l4 = lane >> 4;
  const bf16* Qg = Qb + ((size_t)(b * HQ_ + h) * S_ + qt * 128) * 128;
  const bf16* Kg = Kb + (size_t)(b * HKV_ + hkv) * S_ * 128;
  const bf16* Vg = Vtb + (size_t)(b * HKV_ + hkv) * 128 * S_;

  __shared__ __align__(16) bf16 Ks[2][64 * 128];      // [kk][d], chunk ^= kk&7
  __shared__ __align__(16) bf16 Vs[2][64 * 128];      // [dd][kk], chunk ^= dd&7
  __shared__ __align__(16) uint32_t Ps[128 * 32];     // P^T packed: [q][kk/2], slot ^= (q&7)<<2

  // Q fragments (B-operand): q = wave*32 + qf*16 + l16, d = ks*32 + l4*8..
  bf16x8 qfr[2][4];
#pragma unroll
  for (int qf = 0; qf < 2; ++qf)
#pragma unroll
    for (int ks = 0; ks < 4; ++ks)
      qfr[qf][ks] = *(const bf16x8*)&Qg[(size_t)(wave * 32 + qf * 16 + l16) * 128 +
                                        ks * 32 + l4 * 8];

  // staging pointers (pre-swizzled global source, linear LDS dest)
  const bf16* kp[4]; const bf16* vp[4];
#pragma unroll
  for (int i = 0; i < 4; ++i) {
    int s = i * 256 + t;
    int kr = s >> 4, kc = (s & 15) ^ (kr & 7);
    kp[i] = Kg + (size_t)kr * 128 + kc * 8;
    int vr = s >> 3, vc = (s & 7) ^ (vr & 7);
    vp[i] = Vg + (size_t)vr * S_ + vc * 8;
  }
  auto STAGE = [&](int buf, int nt) {
#pragma unroll
    for (int i = 0; i < 4; ++i) {
      gload16(kp[i] + (size_t)nt * 8192, &Ks[buf][(i * 256 + wave * 64) * 8]);
      gload16(vp[i] + nt * 64, &Vs[buf][(i * 256 + wave * 64) * 8]);
    }
  };

  f32x4 ao[2][8] = {};
  float mrun[2] = {-1e30f, -1e30f}, lrun[2] = {0.f, 0.f};
  const float C = 1.4426950408889634f * 0.08838834764831845f;  // log2(e)/sqrt(128)
  const int qrow[2] = {wave * 32 + l16, wave * 32 + 16 + l16};

  STAGE(0, 0);
  asm volatile("s_waitcnt vmcnt(0)" ::: "memory");
  __syncthreads();

  int cur = 0;
  for (int nt = 0; nt < S_ / 64; ++nt) {
    if (nt < S_ / 64 - 1) STAGE(cur ^ 1, nt + 1);

    // ---- QK^T swapped: scT[nf][qf], kk = nf*16 + l4*4 + rg, q = qf*16 + l16 ----
    f32x4 scT[4][2] = {};
#pragma unroll
    for (int ks = 0; ks < 4; ++ks) {
      bf16x8 kb[4];
#pragma unroll
      for (int nf = 0; nf < 4; ++nf) {
        int row = nf * 16 + l16;
        int ch = (ks * 4 + l4) ^ (row & 7);
        kb[nf] = *(const bf16x8*)&Ks[cur][row * 128 + ch * 8];
      }
#pragma unroll
      for (int nf = 0; nf < 4; ++nf)
#pragma unroll
        for (int qf = 0; qf < 2; ++qf)
          scT[nf][qf] = __builtin_amdgcn_mfma_f32_16x16x32_bf16(kb[nf], qfr[qf][ks],
                                                                scT[nf][qf], 0, 0, 0);
    }

    // ---- softmax: max over raw scores (in-lane 16 + butterfly over l4) ----
    float pmax[2];
#pragma unroll
    for (int qf = 0; qf < 2; ++qf) {
      float v = scT[0][qf][0];
#pragma unroll
      for (int nf = 0; nf < 4; ++nf)
#pragma unroll
        for (int rg = 0; rg < 4; ++rg) v = fmaxf(v, scT[nf][qf][rg]);
      v = fmaxf(v, __shfl_xor(v, 16));
      v = fmaxf(v, __shfl_xor(v, 32));
      pmax[qf] = v * C;  // log2-domain
    }
    // T13 defer-max: only rescale when some row grew > 2^8
    float g = fmaxf(pmax[0] - mrun[0], pmax[1] - mrun[1]);
    if (!__all(g <= 8.0f)) {
#pragma unroll
      for (int qf = 0; qf < 2; ++qf) {
        float mn = fmaxf(mrun[qf], pmax[qf]);
        float al = exp2f(mrun[qf] - mn);
        mrun[qf] = mn;
        lrun[qf] *= al;
#pragma unroll
        for (int df = 0; df < 8; ++df)
#pragma unroll
          for (int rg = 0; rg < 4; ++rg) ao[qf][df][rg] *= al;
      }
    }

    // ---- p = exp2(s*C - m), pack pairs, write P^T to LDS (wave-local) ----
#pragma unroll
    for (int qf = 0; qf < 2; ++qf) {
      int q = qrow[qf];
      float m = mrun[qf], ssum = 0.f;
#pragma unroll
      for (int nf = 0; nf < 4; ++nf) {
        float p0 = exp2f(fmaf(scT[nf][qf][0], C, -m));
        float p1 = exp2f(fmaf(scT[nf][qf][1], C, -m));
        float p2 = exp2f(fmaf(scT[nf][qf][2], C, -m));
        float p3 = exp2f(fmaf(scT[nf][qf][3], C, -m));
        ssum += (p0 + p1) + (p2 + p3);
        uint2 w;
        w.x = pk2(p0, p1);
        w.y = pk2(p2, p3);
        int slot = (nf * 8 + l4 * 2) ^ ((q & 7) << 2);
        *(uint2*)&Ps[q * 32 + slot] = w;
      }
      ssum += __shfl_xor(ssum, 16);
      ssum += __shfl_xor(ssum, 32);
      lrun[qf] += ssum;
    }

    // ---- PV swapped: ao(O^T)[dd][q] += V^T[dd][kk] * P^T[kk][q] ----
#pragma unroll
    for (int ks2 = 0; ks2 < 2; ++ks2) {
      bf16x8 pb[2];
#pragma unroll
      for (int qf = 0; qf < 2; ++qf) {
        int q = qrow[qf];
        int slot = (ks2 * 16 + l4 * 4) ^ ((q & 7) << 2);
        uint4 w = *(const uint4*)&Ps[q * 32 + slot];
        pb[qf] = __builtin_bit_cast(bf16x8, w);
      }
#pragma unroll
      for (int df = 0; df < 8; ++df) {
        int dd = df * 16 + l16;
        int ch = (ks2 * 4 + l4) ^ (dd & 7);
        bf16x8 vb = *(const bf16x8*)&Vs[cur][dd * 64 + ch * 8];
#pragma unroll
        for (int qf = 0; qf < 2; ++qf)
          ao[qf][df] = __builtin_amdgcn_mfma_f32_16x16x32_bf16(vb, pb[qf],
                                                               ao[qf][df], 0, 0, 0);
      }
    }

    asm volatile("s_waitcnt vmcnt(0)" ::: "memory");
    __syncthreads();
    cur ^= 1;
  }

  // ---- epilogue: lane holds O^T[dd=df*16+l4*4+rg][q=qf*16+l16]; 8B stores ----
#pragma unroll
  for (int qf = 0; qf < 2; ++qf) {
    float inv = 1.f / lrun[qf];
    int sg = qt * 128 + wave * 32 + qf * 16 + l16;
#pragma unroll
    for (int df = 0; df < 8; ++df) {
      bf16x4 o;
#pragma unroll
      for (int rg = 0; rg < 4; ++rg) o[rg] = (bf16)(ao[qf][df][rg] * inv);
      *(bf16x4*)&AO[((size_t)(b * S_ + sg)) * D_ + h * 128 + df * 16 + l4 * 4] = o;
    }
  }
}

extern "C" void kernel_launch(void* const* d_in, const int* in_sizes, int n_in,
                              void* d_out, int out_size, void* d_ws, size_t ws_size,
                              hipStream_t stream) {
  const float* x  = (const float*)d_in[0];
  const float* Wq = (const float*)d_in[1];
  const float* Wk = (const float*)d_in[2];
  const float* Wv = (const float*)d_in[3];
  const float* Wo = (const float*)d_in[4];

  char* ws = (char*)d_ws;
  bf16* xb  = (bf16*)(ws + 0);          // 16 MiB  [4096][2048]; reused as AO later
  bf16* Wqt = (bf16*)(ws + 16777216);   // 8 MiB   [2048][2048] (N-major)
  bf16* Wkt = (bf16*)(ws + 25165824);   // 2 MiB   [512][2048]
  bf16* Wvt = (bf16*)(ws + 27262976);   // 2 MiB   [512][2048]
  bf16* Wot = (bf16*)(ws + 29360128);   // 8 MiB   [2048][2048]
  bf16* Qb  = (bf16*)(ws + 37748736);   // 16 MiB  [B,HQ,S,128]
  bf16* Kb  = (bf16*)(ws + 54525952);   // 4 MiB   [B,HKV,S,128]
  bf16* Vtb = (bf16*)(ws + 58720256);   // 4 MiB   [B,HKV,128,S]
  bf16* AO  = xb;                       // alias: xb dead after V projection

  cast_x<<<8192, 256, 0, stream>>>(x, xb, 2097152);
  transW<<<dim3(64, 64), 256, 0, stream>>>(Wq, Wqt, 2048, 2048);
  transW<<<dim3(16, 64), 256, 0, stream>>>(Wk, Wkt, 2048, 512);
  transW<<<dim3(16, 64), 256, 0, stream>>>(Wv, Wvt, 2048, 512);
  transW<<<dim3(64, 64), 256, 0, stream>>>(Wo, Wot, 2048, 2048);

  gemm128<0><<<dim3(16, 32), 256, 0, stream>>>(xb, Wqt, (void*)Qb, 2048, 2048);
  gemm128<1><<<dim3(4, 32), 256, 0, stream>>>(xb, Wkt, (void*)Kb, 2048, 512);
  gemm128<2><<<dim3(4, 32), 256, 0, stream>>>(xb, Wvt, (void*)Vtb, 2048, 512);

  attn_fwd<<<dim3(16, 16, 2), 256, 0, stream>>>(Qb, Kb, Vtb, AO);

  gemm128<3><<<dim3(16, 32), 256, 0, stream>>>(AO, Wot, d_out, 2048, 2048);
}

// Round 4
// 240.959 us; speedup vs baseline: 1.5156x; 1.2481x over previous
//
#include <hip/hip_runtime.h>
#include <stdint.h>

typedef __bf16 bf16;
typedef __attribute__((ext_vector_type(4))) float f32x4;
typedef __attribute__((ext_vector_type(16))) float f32x16;
typedef __attribute__((ext_vector_type(8))) bf16 bf16x8;
typedef __attribute__((ext_vector_type(4))) bf16 bf16x4;
typedef __attribute__((ext_vector_type(4))) float f4;

#define HQ_ 16
#define HKV_ 4
#define S_ 2048
#define D_ 2048

// async global->LDS, 16B per lane. lds_base must be wave-uniform; HW adds lane*16.
static __device__ __forceinline__ void gload16(const void* g, void* lds_base) {
  __builtin_amdgcn_global_load_lds(
      (const __attribute__((address_space(1))) void*)g,
      (__attribute__((address_space(3))) void*)lds_base, 16, 0, 0);
}

static __device__ __forceinline__ uint32_t pk2(float a, float b) {
  uint16_t lo = __builtin_bit_cast(uint16_t, (bf16)a);
  uint16_t hi = __builtin_bit_cast(uint16_t, (bf16)b);
  return (uint32_t)lo | ((uint32_t)hi << 16);
}

// ---------------- cast x: f32 -> bf16, 4 elems/thread ----------------
__global__ __launch_bounds__(256) void cast_x(const float* __restrict__ in,
                                              bf16* __restrict__ out, int n4) {
  int i = blockIdx.x * 256 + threadIdx.x;
  if (i >= n4) return;
  f4 v = *(const f4*)(in + (size_t)i * 4);
  bf16x4 o;
  o[0] = (bf16)v[0]; o[1] = (bf16)v[1]; o[2] = (bf16)v[2]; o[3] = (bf16)v[3];
  *(bf16x4*)(out + (size_t)i * 4) = o;
}

// -------- transpose+cast weights: W[K][N] f32 -> Wt[N][K] bf16 --------
__global__ __launch_bounds__(256) void transW(const float* __restrict__ W,
                                              bf16* __restrict__ Wt, int K, int N) {
  __shared__ float tile[32][33];
  int n0 = blockIdx.x * 32, k0 = blockIdx.y * 32;
  int tx = threadIdx.x & 31, ty = threadIdx.x >> 5;
#pragma unroll
  for (int i = 0; i < 4; ++i)
    tile[ty + i * 8][tx] = W[(size_t)(k0 + ty + i * 8) * N + n0 + tx];
  __syncthreads();
#pragma unroll
  for (int i = 0; i < 4; ++i)
    Wt[(size_t)(n0 + ty + i * 8) * K + k0 + tx] = (bf16)tile[tx][ty + i * 8];
}

// ---------------- bf16 GEMM: C[M,N] = A[M,K] * Bt[N,K]^T ----------------
// 128x128 tile, BK=32, 4 waves (2x2), 16x16x32 MFMA, double-buffered LDS,
// counted vmcnt (no drain in loop), raw s_barrier.
// MODE 3: f32 row-major [M,N].  MODE 4: fused QKV epilogue (Q / K / V^T routing).
template <int MODE>
__global__ __launch_bounds__(256, 3)
void gemm128(const bf16* __restrict__ A, const bf16* __restrict__ Bt,
             void* __restrict__ out, void* __restrict__ out2,
             void* __restrict__ out3, int K, int N) {
  __shared__ __align__(16) bf16 As[2][128 * 32];
  __shared__ __align__(16) bf16 Bs[2][128 * 32];
  const int t = threadIdx.x;
  const int lane = t & 63, wave = t >> 6;
  const int l16 = lane & 15, l4 = lane >> 4;
  const int wr = wave >> 1, wc = wave & 1;
  const int m0 = blockIdx.y * 128, n0 = blockIdx.x * 128;

  f32x4 acc[4][4] = {};

  // staging: slot s in 0..511 per matrix; row = s>>2 (32-elem rows), chunk = s&3
  // swizzle: LDS chunk c holds global chunk c ^ ((row>>1)&3)
  const int r0 = t >> 2, c0 = ((t & 3) ^ ((t >> 3) & 3));
  const int r1 = r0 + 64, c1 = ((t & 3) ^ ((r1 >> 1) & 3));
  const bf16* aS0 = A + (size_t)(m0 + r0) * K + c0 * 8;
  const bf16* aS1 = A + (size_t)(m0 + r1) * K + c1 * 8;
  const bf16* bS0 = Bt + (size_t)(n0 + r0) * K + c0 * 8;
  const bf16* bS1 = Bt + (size_t)(n0 + r1) * K + c1 * 8;

  const int nk = K >> 5;
  auto STAGE = [&](int buf, int kt) {
    gload16(aS0 + (size_t)kt * 32, &As[buf][(wave * 64) * 8]);
    gload16(aS1 + (size_t)kt * 32, &As[buf][(256 + wave * 64) * 8]);
    gload16(bS0 + (size_t)kt * 32, &Bs[buf][(wave * 64) * 8]);
    gload16(bS1 + (size_t)kt * 32, &Bs[buf][(256 + wave * 64) * 8]);
  };

  STAGE(0, 0);
  int cb = 0;
  for (int kt = 0; kt < nk; ++kt) {
    int kn = kt + 1; if (kn == nk) kn = 0;
    STAGE(cb ^ 1, kn);
    asm volatile("s_waitcnt vmcnt(4)" ::: "memory");
    __builtin_amdgcn_s_barrier();
    bf16x8 af[4], bb[4];
#pragma unroll
    for (int mf = 0; mf < 4; ++mf) {
      int row = wr * 64 + mf * 16 + l16;
      af[mf] = *(const bf16x8*)&As[cb][row * 32 + (l4 ^ ((row >> 1) & 3)) * 8];
    }
#pragma unroll
    for (int nf = 0; nf < 4; ++nf) {
      int row = wc * 64 + nf * 16 + l16;
      bb[nf] = *(const bf16x8*)&Bs[cb][row * 32 + (l4 ^ ((row >> 1) & 3)) * 8];
    }
#pragma unroll
    for (int mf = 0; mf < 4; ++mf)
#pragma unroll
      for (int nf = 0; nf < 4; ++nf)
        acc[mf][nf] = __builtin_amdgcn_mfma_f32_16x16x32_bf16(af[mf], bb[nf],
                                                              acc[mf][nf], 0, 0, 0);
    __builtin_amdgcn_s_barrier();
    cb ^= 1;
  }

#pragma unroll
  for (int mf = 0; mf < 4; ++mf)
#pragma unroll
    for (int nf = 0; nf < 4; ++nf)
#pragma unroll
      for (int rg = 0; rg < 4; ++rg) {
        int r = m0 + wr * 64 + mf * 16 + l4 * 4 + rg;  // token index
        int c = n0 + wc * 64 + nf * 16 + l16;          // output column
        float v = acc[mf][nf][rg];
        if constexpr (MODE == 4) {
          int b = r >> 11, s = r & 2047;
          if (c < 2048) {                // Q: [B,HQ,S,128]
            int h = c >> 7, dd = c & 127;
            ((bf16*)out)[(((size_t)(b * HQ_ + h)) * S_ + s) * 128 + dd] = (bf16)v;
          } else if (c < 2560) {         // K: [B,HKV,S,128]
            int cc = c - 2048, h = cc >> 7, dd = cc & 127;
            ((bf16*)out2)[(((size_t)(b * HKV_ + h)) * S_ + s) * 128 + dd] = (bf16)v;
          } else {                       // V^T: [B,HKV,128,S]
            int cc = c - 2560, h = cc >> 7, dd = cc & 127;
            ((bf16*)out3)[(((size_t)(b * HKV_ + h)) * 128 + dd) * S_ + s] = (bf16)v;
          }
        } else {
          ((float*)out)[(size_t)r * N + c] = v;
        }
      }
}

// ---------------- flash attention, 32x32 MFMA, in-register P ----------------
// grid (S/128, HQ, B); 256 thr = 4 waves; wave owns 32 q-rows; KV tile = 64.
// S^T = mfma_32x32x16(K, Q): lane l, reg r: kk = (r&3)+8*(r>>2)+4*(l>>5)+32*kf,
// q = wave*32 + (l&31). P redistributed to PV B-operand by permlane32_swap.
// O^T = mfma_32x32x16(V^T, P^T).
__global__ __launch_bounds__(256, 2)
void attn_fwd(const bf16* __restrict__ Qb, const bf16* __restrict__ Kb,
              const bf16* __restrict__ Vtb, bf16* __restrict__ AO) {
  const int qt = blockIdx.x, h = blockIdx.y, b = blockIdx.z;
  const int hkv = h >> 2;  // REP = 4
  const int t = threadIdx.x, lane = t & 63, wave = t >> 6;
  const int l31 = lane & 31, l32 = lane >> 5;
  const bf16* Qg = Qb + ((size_t)(b * HQ_ + h) * S_ + qt * 128) * 128;
  const bf16* Kg = Kb + (size_t)(b * HKV_ + hkv) * S_ * 128;
  const bf16* Vg = Vtb + (size_t)(b * HKV_ + hkv) * 128 * S_;

  __shared__ __align__(16) bf16 Ks[2][64 * 128];   // [kk][d], 16B-chunk ^= kk&15
  __shared__ __align__(16) bf16 Vs[2][128 * 64];   // [dd][kk], 16B-chunk ^= dd&7

  // Q frags (B-operand): lane: Q[q = wave*32 + l31][d = ds*16 + l32*8 + e]
  bf16x8 qfr[8];
#pragma unroll
  for (int ds = 0; ds < 8; ++ds)
    qfr[ds] = *(const bf16x8*)&Qg[(size_t)(wave * 32 + l31) * 128 + ds * 16 + l32 * 8];
  asm volatile("s_waitcnt vmcnt(0)" ::: "memory");  // drain Q so vmcnt counts stay exact

  // staging bases (pre-swizzled global source, linear LDS dest)
  const bf16* kp[4]; const bf16* vp[4];
#pragma unroll
  for (int i = 0; i < 4; ++i) {
    int s = i * 256 + t;
    int kr = s >> 4, klc = (s & 15) ^ (kr & 15);
    kp[i] = Kg + (size_t)kr * 128 + klc * 8;
    int vr = s >> 3, vlc = (s & 7) ^ (vr & 7);
    vp[i] = Vg + (size_t)vr * S_ + vlc * 8;
  }
  auto STAGE = [&](int buf, int nt) {
#pragma unroll
    for (int i = 0; i < 4; ++i) {
      gload16(kp[i] + (size_t)nt * 8192, &Ks[buf][(i * 256 + wave * 64) * 8]);
      gload16(vp[i] + nt * 64, &Vs[buf][(i * 256 + wave * 64) * 8]);
    }
  };

  f32x16 ao[4] = {};
  float mrun = -1e30f, lrun = 0.f;
  const float C = 1.4426950408889634f * 0.08838834764831845f;  // log2(e)/sqrt(128)

  STAGE(0, 0);
  int cur = 0;
  for (int nt = 0; nt < S_ / 64; ++nt) {
    int nn = nt + 1; if (nn == S_ / 64) nn = 0;   // wrap keeps vmcnt counts uniform
    STAGE(cur ^ 1, nn);
    asm volatile("s_waitcnt vmcnt(8)" ::: "memory");  // tile nt's 8 loads landed
    __builtin_amdgcn_s_barrier();

    // ---- QK^T: scT[kf] += mfma(K-frag, Q-frag) ----
    f32x16 scT[2] = {};
    __builtin_amdgcn_s_setprio(1);
#pragma unroll
    for (int ds = 0; ds < 8; ++ds) {
      int lc = ds * 2 + l32;
      bf16x8 kb0 = *(const bf16x8*)&Ks[cur][l31 * 128 + (lc ^ (l31 & 15)) * 8];
      bf16x8 kb1 = *(const bf16x8*)&Ks[cur][(32 + l31) * 128 + (lc ^ (l31 & 15)) * 8];
      scT[0] = __builtin_amdgcn_mfma_f32_32x32x16_bf16(kb0, qfr[ds], scT[0], 0, 0, 0);
      scT[1] = __builtin_amdgcn_mfma_f32_32x32x16_bf16(kb1, qfr[ds], scT[1], 0, 0, 0);
    }
    __builtin_amdgcn_s_setprio(0);

    // ---- softmax over the lane's 32 scores (one q-row half; halves share q) ----
    float mx = scT[0][0];
#pragma unroll
    for (int kf = 0; kf < 2; ++kf)
#pragma unroll
      for (int r = 0; r < 16; ++r) mx = fmaxf(mx, scT[kf][r]);
    mx = fmaxf(mx, __shfl_xor(mx, 32));
    float pmax = mx * C;  // log2 domain
    if (!__all(pmax - mrun <= 8.0f)) {   // T13 defer-max
      float mn = fmaxf(mrun, pmax);
      float al = exp2f(mrun - mn);
      mrun = mn; lrun *= al;
#pragma unroll
      for (int df = 0; df < 4; ++df)
#pragma unroll
        for (int r = 0; r < 16; ++r) ao[df][r] *= al;
    }
    float ssum = 0.f;
#pragma unroll
    for (int kf = 0; kf < 2; ++kf)
#pragma unroll
      for (int r = 0; r < 16; ++r) {
        float pv = exp2f(fmaf(scT[kf][r], C, -mrun));
        scT[kf][r] = pv;
        ssum += pv;
      }
    ssum += __shfl_xor(ssum, 32);
    lrun += ssum;

    // ---- pack P to bf16 pairs: u[kf][g][j] = (kk = 32kf+8g+4*l32+2j, +1) ----
    uint32_t u[2][4][2];
#pragma unroll
    for (int kf = 0; kf < 2; ++kf)
#pragma unroll
      for (int g = 0; g < 4; ++g)
#pragma unroll
        for (int j = 0; j < 2; ++j)
          u[kf][g][j] = pk2(scT[kf][g * 4 + 2 * j], scT[kf][g * 4 + 2 * j + 1]);

    // ---- permlane32_swap -> PV B-frags pb[ks]: P^T[kk=ks*16+l32*8+e][q] ----
    bf16x8 pb[4];
#pragma unroll
    for (int ks = 0; ks < 4; ++ks) {
      int kf = ks >> 1, bb = ks & 1;
      uint32_t d0 = u[kf][2 * bb][0], s0 = u[kf][2 * bb + 1][0];
      uint32_t d1 = u[kf][2 * bb][1], s1 = u[kf][2 * bb + 1][1];
      asm volatile("v_permlane32_swap_b32 %0, %1" : "+v"(d0), "+v"(s0));
      asm volatile("v_permlane32_swap_b32 %0, %1" : "+v"(d1), "+v"(s1));
      uint4 w; w.x = d0; w.y = d1; w.z = s0; w.w = s1;
      pb[ks] = __builtin_bit_cast(bf16x8, w);
    }

    // ---- PV: ao[df] += mfma(V^T-frag, pb[ks]) ----
    __builtin_amdgcn_s_setprio(1);
#pragma unroll
    for (int ks = 0; ks < 4; ++ks) {
      int lc = ks * 2 + l32;
#pragma unroll
      for (int df = 0; df < 4; ++df) {
        int row = df * 32 + l31;
        bf16x8 va = *(const bf16x8*)&Vs[cur][row * 64 + (lc ^ (l31 & 7)) * 8];
        ao[df] = __builtin_amdgcn_mfma_f32_32x32x16_bf16(va, pb[ks], ao[df], 0, 0, 0);
      }
    }
    __builtin_amdgcn_s_setprio(0);

    __builtin_amdgcn_s_barrier();  // all reads of bufs[cur] done -> next stage may overwrite
    cur ^= 1;
  }

  // ---- epilogue: lane holds O^T[dd = df*32 + 8g + 4*l32 + j][q]; 8B stores ----
  float inv = 1.f / lrun;
  bf16* aop = AO + ((size_t)(b * S_ + qt * 128 + wave * 32 + l31)) * D_ + h * 128;
#pragma unroll
  for (int df = 0; df < 4; ++df)
#pragma unroll
    for (int g = 0; g < 4; ++g) {
      bf16x4 o;
#pragma unroll
      for (int j = 0; j < 4; ++j) o[j] = (bf16)(ao[df][4 * g + j] * inv);
      *(bf16x4*)&aop[df * 32 + 8 * g + 4 * l32] = o;
    }
}

extern "C" void kernel_launch(void* const* d_in, const int* in_sizes, int n_in,
                              void* d_out, int out_size, void* d_ws, size_t ws_size,
                              hipStream_t stream) {
  const float* x  = (const float*)d_in[0];
  const float* Wq = (const float*)d_in[1];
  const float* Wk = (const float*)d_in[2];
  const float* Wv = (const float*)d_in[3];
  const float* Wo = (const float*)d_in[4];

  char* ws = (char*)d_ws;
  bf16* xb  = (bf16*)(ws + 0);          // 16 MiB  [4096][2048]; reused as AO later
  bf16* Wqt = (bf16*)(ws + 16777216);   // 8 MiB   [2048][2048] (N-major)  } contiguous
  bf16* Wkt = (bf16*)(ws + 25165824);   // 2 MiB   [512][2048]             } 3072-row
  bf16* Wvt = (bf16*)(ws + 27262976);   // 2 MiB   [512][2048]             } QKV weight
  bf16* Wot = (bf16*)(ws + 29360128);   // 8 MiB   [2048][2048]
  bf16* Qb  = (bf16*)(ws + 37748736);   // 16 MiB  [B,HQ,S,128]
  bf16* Kb  = (bf16*)(ws + 54525952);   // 4 MiB   [B,HKV,S,128]
  bf16* Vtb = (bf16*)(ws + 58720256);   // 4 MiB   [B,HKV,128,S]
  bf16* AO  = xb;                       // alias: xb dead after QKV projection

  cast_x<<<8192, 256, 0, stream>>>(x, xb, 2097152);
  transW<<<dim3(64, 64), 256, 0, stream>>>(Wq, Wqt, 2048, 2048);
  transW<<<dim3(16, 64), 256, 0, stream>>>(Wk, Wkt, 2048, 512);
  transW<<<dim3(16, 64), 256, 0, stream>>>(Wv, Wvt, 2048, 512);
  transW<<<dim3(64, 64), 256, 0, stream>>>(Wo, Wot, 2048, 2048);

  // fused QKV projection: Bt = [Wqt; Wkt; Wvt] (3072 rows, contiguous)
  gemm128<4><<<dim3(24, 32), 256, 0, stream>>>(xb, Wqt, (void*)Qb, (void*)Kb,
                                               (void*)Vtb, 2048, 3072);

  attn_fwd<<<dim3(16, 16, 2), 256, 0, stream>>>(Qb, Kb, Vtb, AO);

  gemm128<3><<<dim3(16, 32), 256, 0, stream>>>(AO, Wot, d_out, nullptr, nullptr,
                                               2048, 2048);
}